// Round 7
// baseline (316.253 us; speedup 1.0000x reference)
//
#include <hip/hip_runtime.h>

#define Bn 8
#define Nn 4096
#define Pn 4096
#define Kn 32
#define Cn 128

using float4v = __attribute__((ext_vector_type(4))) float;
using short8  = __attribute__((ext_vector_type(8))) short;

__device__ __forceinline__ unsigned short bf16b(float f) {
  union { float f; unsigned u; } v; v.f = f;
  unsigned r = v.u + 0x7FFFu + ((v.u >> 16) & 1u);   // round-nearest-even
  return (unsigned short)(r >> 16);
}

// (hi16(x)) | (hi16(y)<<16) — truncating f32->bf16 pair pack, one v_perm_b32
__device__ __forceinline__ unsigned pkhi(float x, float y) {
  return __builtin_amdgcn_perm(__float_as_uint(y), __float_as_uint(x), 0x07060302u);
}

// ---------------------------------------------------------------------------
// prep: WlT[n][k] = bf16(Wl[k][n])   (2048x128 -> 128x2048), 16 blocks
// ---------------------------------------------------------------------------
__global__ __launch_bounds__(256) void prep_wl(const float* __restrict__ Wl,
                                               unsigned short* __restrict__ WlT) {
  __shared__ unsigned short tile[128 * 130];
  const int t = threadIdx.x, blk = blockIdx.x;
#pragma unroll
  for (int i = 0; i < 64; ++i) {
    int idx = i * 256 + t;
    int kl = idx >> 7, n = idx & 127;
    tile[n * 130 + kl] = bf16b(Wl[(size_t)(blk * 128 + kl) * 128 + n]);
  }
  __syncthreads();
#pragma unroll
  for (int i = 0; i < 64; ++i) {
    int idx = i * 256 + t;
    int n = idx >> 7, kl = idx & 127;
    WlT[(size_t)n * 2048 + blk * 128 + kl] = tile[n * 130 + kl];
  }
}

// ---------------------------------------------------------------------------
// fused: 16 points/block. Stage1 (per wave, 4 pts): coalesced row gather ->
// 4 KB half-width slab transpose (round-6 verified pattern, width 64) ->
// MFMA -> Mlds[16][2048] bf16 (16B-chunk XOR swizzle, key=row&7). One
// __syncthreads. Stage2 (barrier-free): 64 K-steps, A b128 from Mlds,
// B direct from L2-resident WlT, 2 MFMA/iter/wave. LDS = exactly 80 KB
// -> 2 blocks/CU; the two resident blocks' phases overlap.
// ---------------------------------------------------------------------------
__global__ __launch_bounds__(256, 2) void fused(
    const float* __restrict__ points, const float* __restrict__ lc,
    const int* __restrict__ nl, const int* __restrict__ didx,
    const float* __restrict__ Ww, const float* __restrict__ bwv,
    const unsigned short* __restrict__ WlT, const float* __restrict__ blv,
    float* __restrict__ xout, float* __restrict__ gacc) {
  __shared__ __align__(16) unsigned char smem[81920];  // 64K Mlds + 16K slabs

  const int t = threadIdx.x, lane = t & 63, wave = t >> 6;
  const int l15 = lane & 15, q = lane >> 4;
  const int bidx = blockIdx.x & 7;            // XCD-affine batch
  const int p0 = (blockIdx.x >> 3) * 16;
  const int db = didx[bidx];
  const float* __restrict__ pbat = points + (size_t)db * Nn * Cn;
  unsigned short* __restrict__ slab =
      (unsigned short*)(smem + 65536) + wave * 2048;   // 4 KB per wave
  float* __restrict__ red = (float*)(smem + 65536);    // overlaid (epilogue)

  const float Ww0 = Ww[l15], Ww1 = Ww[16 + l15], Ww2 = Ww[32 + l15];
  const float bw0 = bwv[l15];
  const int lh = lane >> 5, l31 = lane & 31;

  // ---------------- stage 1 ----------------
  for (int pi = 0; pi < 4; ++pi) {
    const int pl = wave * 4 + pi;              // Mlds row / local point
    const int p = p0 + pl;
    const size_t pk = (size_t)(db * Pn + p) * Kn;
    int nk[32];
    const int4* __restrict__ nl4 = (const int4*)(nl + pk);
#pragma unroll
    for (int i = 0; i < 8; ++i) *(int4*)&nk[i * 4] = nl4[i];
    // weight A-frag: A[m=w=l15][k=q*8+j]
    const float* __restrict__ lcp = lc + (pk + q * 8) * 3;
    float la[24];
#pragma unroll
    for (int v = 0; v < 6; ++v) *(float4v*)&la[v * 4] = *(const float4v*)(lcp + v * 4);
    short8 af;
#pragma unroll
    for (int j = 0; j < 8; ++j) {
      float w = bw0 + la[3 * j] * Ww0 + la[3 * j + 1] * Ww1 + la[3 * j + 2] * Ww2;
      af[j] = (short)bf16b(w);
    }
#pragma unroll
    for (int h = 0; h < 2; ++h) {              // c-halves [0,64), [64,128)
      __builtin_amdgcn_wave_barrier();
      // gather: inst i covers rows (2i, 2i+1) split across half-waves,
      // float2/lane -> trunc pk -> rotated slab [k][c'] (conflict-free)
#pragma unroll
      for (int i = 0; i < 16; ++i) {
        const int rv = (lane & 32) ? nk[2 * i + 1] : nk[2 * i];
        const float2 v =
            *(const float2*)(pbat + (size_t)rv * Cn + h * 64 + l31 * 2);
        const int rot = ((2 * i) >> 3) * 16;   // compile-time
        const int cpr = (l31 * 2 + rot) & 63;
        *(unsigned*)&slab[(2 * i + lh) * 64 + cpr] = pkhi(v.x, v.y);
      }
      __builtin_amdgcn_wave_barrier();
#pragma unroll
      for (int ctl = 0; ctl < 4; ++ctl) {
        const int ct = h * 4 + ctl;
        const int coff = (ctl * 16 + l15 + q * 16) & 63;
        short8 bfv;
#pragma unroll
        for (int j = 0; j < 8; ++j)
          bfv[j] = (short)slab[(q * 8 + j) * 64 + coff];
        float4v d = {0.f, 0.f, 0.f, 0.f};
        d = __builtin_amdgcn_mfma_f32_16x16x32_bf16(af, bfv, d, 0, 0, 0);
        // lane holds M[pl][j_M = (ct*16+l15)*16 + q*4 + r]
        const unsigned c16 = (unsigned)((ct * 16 + l15) * 2 + (q >> 1));
        const unsigned pos = c16 ^ (unsigned)(pl & 7);
        uint2 u;
        u.x = pkhi(d[0], d[1]);
        u.y = pkhi(d[2], d[3]);
        *(uint2*)(smem + pl * 4096 + pos * 16 + (q & 1) * 8) = u;
      }
    }
  }
  __syncthreads();

  // ---------------- stage 2 (barrier-free) ----------------
  const int n0 = wave * 32;
  const unsigned short* __restrict__ b0p = WlT + (size_t)(n0 + l15) * 2048 + q * 8;
  float4v acc0 = {0.f, 0.f, 0.f, 0.f}, acc1 = {0.f, 0.f, 0.f, 0.f};
#pragma unroll 8
  for (int kk = 0; kk < 64; ++kk) {
    const unsigned pos = ((unsigned)(kk * 4 + q)) ^ (unsigned)(l15 & 7);
    short8 a = *(const short8*)(smem + l15 * 4096 + pos * 16);
    short8 b0 = *(const short8*)(b0p + kk * 32);
    short8 b1 = *(const short8*)(b0p + 16 * 2048 + kk * 32);
    acc0 = __builtin_amdgcn_mfma_f32_16x16x32_bf16(a, b0, acc0, 0, 0, 0);
    acc1 = __builtin_amdgcn_mfma_f32_16x16x32_bf16(a, b1, acc1, 0, 0, 0);
  }

  // epilogue: bias, transposed store (B,C,P), block-reduced channel stats
  __syncthreads();                    // slab region dead -> reuse as red[]
  float4v accs[2] = {acc0, acc1};
#pragma unroll
  for (int nt = 0; nt < 2; ++nt) {
    const int ch = n0 + nt * 16 + l15;
    const float bb = blv[ch];
    float4v o;
    float s = 0.f, sq = 0.f;
#pragma unroll
    for (int r = 0; r < 4; ++r) {
      float v = accs[nt][r] + bb; o[r] = v; s += v; sq += v * v;
    }
    *(float4v*)(xout + ((size_t)bidx * Cn + ch) * Pn + p0 + q * 4) = o;
    s += __shfl_xor(s, 16); s += __shfl_xor(s, 32);
    sq += __shfl_xor(sq, 16); sq += __shfl_xor(sq, 32);
    if (lane < 16) { red[ch] = s; red[128 + ch] = sq; }
  }
  __syncthreads();
  atomicAdd(&gacc[t], red[t]);
}

// ---------------------------------------------------------------------------
// finalize: layernorm (per-channel over B*P) + relu, in place on x chunk
// ---------------------------------------------------------------------------
__global__ __launch_bounds__(256) void finalize_ln(float* __restrict__ x,
                                                   const float* __restrict__ gacc,
                                                   const float* __restrict__ gamma,
                                                   const float* __restrict__ beta) {
  const int idx = blockIdx.x * 256 + threadIdx.x;
  const int fi = idx * 4;
  const int c = (fi >> 12) & 127;
  const float inv = 1.f / 32768.f;
  const float mean = gacc[c] * inv;
  const float var = gacc[128 + c] * inv - mean * mean;
  const float scale = rsqrtf(var + 1e-5f) * gamma[c];
  const float shift = beta[c] - mean * scale;
  float4v v = *(float4v*)(x + fi);
#pragma unroll
  for (int r = 0; r < 4; ++r) v[r] = fmaxf(v[r] * scale + shift, 0.f);
  *(float4v*)(x + fi) = v;
}

extern "C" void kernel_launch(void* const* d_in, const int* in_sizes, int n_in,
                              void* d_out, int out_size, void* d_ws, size_t ws_size,
                              hipStream_t stream) {
  const float* xyz    = (const float*)d_in[0];
  const float* points = (const float*)d_in[1];
  const float* lc     = (const float*)d_in[2];
  const int*   nl     = (const int*)d_in[3];
  const int*   didx   = (const int*)d_in[4];
  const float* Ww     = (const float*)d_in[5];
  const float* bw     = (const float*)d_in[6];
  const float* Wl     = (const float*)d_in[7];
  const float* bl     = (const float*)d_in[8];
  const float* gamma  = (const float*)d_in[9];
  const float* beta   = (const float*)d_in[10];

  float* out  = (float*)d_out;
  float* xout = out + (size_t)Bn * Pn * 3;                   // x chunk (B,C,P)
  unsigned short* WlT = (unsigned short*)d_ws;               // 512 KB
  float* gacc = (float*)((char*)d_ws + (size_t)512 * 1024);  // 1 KB

  hipMemcpyAsync(out, xyz, (size_t)Bn * Pn * 3 * sizeof(float),
                 hipMemcpyDeviceToDevice, stream);
  hipMemsetAsync(gacc, 0, 256 * sizeof(float), stream);
  prep_wl<<<16, 256, 0, stream>>>(Wl, WlT);
  fused<<<2048, 256, 0, stream>>>(points, lc, nl, didx, Ww, bw, WlT, bl,
                                  xout, gacc);
  finalize_ln<<<4096, 256, 0, stream>>>(xout, gacc, gamma, beta);
}

// Round 8
// 212.408 us; speedup vs baseline: 1.4889x; 1.4889x over previous
//
#include <hip/hip_runtime.h>

#define Bn 8
#define Nn 4096
#define Pn 4096
#define Kn 32
#define Cn 128

using float4v = __attribute__((ext_vector_type(4))) float;
using short8  = __attribute__((ext_vector_type(8))) short;

__device__ __forceinline__ unsigned short bf16b(float f) {
  union { float f; unsigned u; } v; v.f = f;
  unsigned r = v.u + 0x7FFFu + ((v.u >> 16) & 1u);   // round-nearest-even
  return (unsigned short)(r >> 16);
}

// (hi16(x)) | (hi16(y)<<16) — truncating f32->bf16 pair pack, one v_perm_b32
__device__ __forceinline__ unsigned pkhi(float x, float y) {
  return __builtin_amdgcn_perm(__float_as_uint(y), __float_as_uint(x), 0x07060302u);
}

__device__ __forceinline__ void gld_lds16(const void* g, void* l) {
  __builtin_amdgcn_global_load_lds(
      (const __attribute__((address_space(1))) unsigned int*)g,
      (__attribute__((address_space(3))) unsigned int*)l, 16, 0, 0);
}

// ---------------------------------------------------------------------------
// prep: blocks 0-15: WlT[n][k] = bf16(Wl[k][n]); blocks 16-47: xyz copy into
// d_out (+ block 16 zeroes gacc). Folds 2 extra dispatches away.
// ---------------------------------------------------------------------------
__global__ __launch_bounds__(256) void prep(const float* __restrict__ Wl,
                                            unsigned short* __restrict__ WlT,
                                            const float* __restrict__ xyz,
                                            float* __restrict__ out,
                                            float* __restrict__ gacc) {
  __shared__ unsigned short tile[128 * 130];
  const int t = threadIdx.x, blk = blockIdx.x;
  if (blk < 16) {
#pragma unroll
    for (int i = 0; i < 64; ++i) {
      int idx = i * 256 + t;
      int kl = idx >> 7, n = idx & 127;
      tile[n * 130 + kl] = bf16b(Wl[(size_t)(blk * 128 + kl) * 128 + n]);
    }
    __syncthreads();
#pragma unroll
    for (int i = 0; i < 64; ++i) {
      int idx = i * 256 + t;
      int n = idx >> 7, kl = idx & 127;
      WlT[(size_t)n * 2048 + blk * 128 + kl] = tile[n * 130 + kl];
    }
  } else {
    if (blk == 16) gacc[t] = 0.f;
    const int i0 = (blk - 16) * 3072 + t * 12;   // 32 blocks x 3072 f32 = 98304
#pragma unroll
    for (int i = 0; i < 3; ++i)
      *(float4v*)(out + i0 + i * 4) = *(const float4v*)(xyz + i0 + i * 4);
  }
}

// ---------------------------------------------------------------------------
// stage1: single-wave blocks (8192 blocks -> up to 20 resident/CU) for
// latency hiding via block-level parallelism. Verified round-6 slab
// transpose + wave_barrier fences; trunc v_perm packs; 32-bit voffsets.
// ---------------------------------------------------------------------------
__global__ __launch_bounds__(64) void stage1(
    const float* __restrict__ points, const float* __restrict__ lc,
    const int* __restrict__ nl, const int* __restrict__ didx,
    const float* __restrict__ Ww, const float* __restrict__ bwv,
    unsigned short* __restrict__ Mglob) {
  __shared__ unsigned short slab[32 * 128];   // 8 KB

  const int lane = threadIdx.x;               // one wave per block
  const int l15 = lane & 15, q = lane >> 4;
  const int b = blockIdx.x & 7;               // XCD-affine batch
  const int pg = blockIdx.x >> 3;             // 0..1023, 4 points
  const int db = didx[b];
  const float2* __restrict__ pbat2 =
      (const float2*)(points + (size_t)db * Nn * Cn);
  const float Ww0 = Ww[l15], Ww1 = Ww[16 + l15], Ww2 = Ww[32 + l15];
  const float bw0 = bwv[l15];

  for (int pi = 0; pi < 4; ++pi) {
    const int p = pg * 4 + pi;
    const unsigned pk = (unsigned)((db * Pn + p) * Kn);
    // all 32 neighbor ids (broadcast int4 loads -> VGPRs)
    int nk[32];
    const int4* __restrict__ nl4 = (const int4*)(nl + pk);
#pragma unroll
    for (int i = 0; i < 8; ++i) *(int4*)&nk[i * 4] = nl4[i];
    // weight A-frag: A[m=w=l15][k=q*8+j]  (RNE — cheap, 8 values)
    const float* __restrict__ lcp = lc + (size_t)(pk + q * 8) * 3;
    float la[24];
#pragma unroll
    for (int v = 0; v < 6; ++v) *(float4v*)&la[v * 4] = *(const float4v*)(lcp + v * 4);
    short8 af;
#pragma unroll
    for (int j = 0; j < 8; ++j) {
      float w = bw0 + la[3 * j] * Ww0 + la[3 * j + 1] * Ww1 + la[3 * j + 2] * Ww2;
      af[j] = (short)bf16b(w);
    }
    // fence: prior iteration's slab reads must not sink below these writes
    __builtin_amdgcn_wave_barrier();
    // coalesced row loads -> rotated slab [k][c]   (verified round-6 pattern)
#pragma unroll
    for (int r = 0; r < 32; ++r) {
      const float2 v = pbat2[((unsigned)nk[r] << 6) + lane];
      const unsigned idx = r * 128 + ((lane * 2 + (r >> 3) * 16) & 127);
      *(unsigned*)&slab[idx] = pkhi(v.x, v.y);
    }
    __builtin_amdgcn_wave_barrier();
    // frags + MFMA + contiguous 512-B M-row stores (32-bit offset)
    const unsigned moff = ((unsigned)(b * Pn + p)) << 11;
#pragma unroll
    for (int ct = 0; ct < 8; ++ct) {
      const int coff = (ct * 16 + l15 + q * 16) & 127;
      short8 bfv;
#pragma unroll
      for (int j = 0; j < 8; ++j)
        bfv[j] = (short)slab[(q * 8 + j) * 128 + coff];
      float4v d = {0.f, 0.f, 0.f, 0.f};
      d = __builtin_amdgcn_mfma_f32_16x16x32_bf16(af, bfv, d, 0, 0, 0);
      uint2 u;
      u.x = pkhi(d[0], d[1]);
      u.y = pkhi(d[2], d[3]);
      *(uint2*)&Mglob[moff + (ct * 16 + l15) * 16 + q * 4] = u;
    }
    __builtin_amdgcn_wave_barrier();
  }
}

// ---------------------------------------------------------------------------
// stage2: Y(32768x128) = M(32768x2048) @ Wl(2048x128).   (round-6 verified)
// 1024 blocks, 32 rows x 128 n; BK=64 staged via global_load_lds(16B) with
// XOR chunk swizzle; wave = 32 rows x 32 n (8 b128 frag reads / kk).
// ---------------------------------------------------------------------------
__global__ __launch_bounds__(256) void stage2(
    const unsigned short* __restrict__ Mglob,
    const unsigned short* __restrict__ WlT, const float* __restrict__ blv,
    float* __restrict__ xout, float* __restrict__ gacc) {
  __shared__ unsigned short As[32 * 64];    // 4 KB
  __shared__ unsigned short Bs[128 * 64];   // 16 KB
  __shared__ float red[256];

  const int t = threadIdx.x, lane = t & 63, wave = t >> 6;
  const int l15 = lane & 15, q = lane >> 4;
  const int lr = lane >> 3, lchk = lane & 7;
  const int bidx = blockIdx.x & 7;                 // XCD-affine batch
  const int pt0 = (blockIdx.x >> 3) * 32;
  const size_t row0 = (size_t)bidx * Pn + pt0;

  float4v acc[2][2];
#pragma unroll
  for (int rt = 0; rt < 2; ++rt)
#pragma unroll
    for (int nt = 0; nt < 2; ++nt) acc[rt][nt] = (float4v){0.f, 0.f, 0.f, 0.f};

  for (int kk = 0; kk < 32; ++kk) {
    const int k0 = kk * 64;
    gld_lds16(Mglob + (row0 + wave * 8 + lr) * 2048 + k0 + (lchk ^ lr) * 8,
              &As[wave * 8 * 64]);
#pragma unroll
    for (int it = 0; it < 4; ++it) {
      const int n = wave * 32 + it * 8 + lr;
      gld_lds16(WlT + (size_t)n * 2048 + k0 + (lchk ^ lr) * 8,
                &Bs[(wave * 32 + it * 8) * 64]);
    }
    __syncthreads();
#pragma unroll
    for (int ks = 0; ks < 2; ++ks) {
      short8 a[2], bq[2];
#pragma unroll
      for (int rt = 0; rt < 2; ++rt) {
        const int row = rt * 16 + l15;
        a[rt] = *(const short8*)&As[row * 64 + (((ks * 4 + q) ^ (row & 7)) << 3)];
      }
#pragma unroll
      for (int nt = 0; nt < 2; ++nt) {
        const int n = wave * 32 + nt * 16 + l15;
        bq[nt] = *(const short8*)&Bs[n * 64 + (((ks * 4 + q) ^ (n & 7)) << 3)];
      }
#pragma unroll
      for (int rt = 0; rt < 2; ++rt)
#pragma unroll
        for (int nt = 0; nt < 2; ++nt)
          acc[rt][nt] = __builtin_amdgcn_mfma_f32_16x16x32_bf16(a[rt], bq[nt],
                                                                acc[rt][nt], 0, 0, 0);
    }
    __syncthreads();
  }

  // epilogue: bias, transposed store (B,C,P), disjoint per-wave channel stats
#pragma unroll
  for (int nt = 0; nt < 2; ++nt) {
    const int ch = wave * 32 + nt * 16 + l15;
    const float bb = blv[ch];
    float s = 0.f, sq = 0.f;
#pragma unroll
    for (int rt = 0; rt < 2; ++rt) {
      float4v o;
#pragma unroll
      for (int r = 0; r < 4; ++r) {
        float v = acc[rt][nt][r] + bb; o[r] = v; s += v; sq += v * v;
      }
      *(float4v*)(xout + ((size_t)bidx * Cn + ch) * Pn + pt0 + rt * 16 + q * 4) = o;
    }
    s += __shfl_xor(s, 16); s += __shfl_xor(s, 32);
    sq += __shfl_xor(sq, 16); sq += __shfl_xor(sq, 32);
    if (lane < 16) { red[ch] = s; red[128 + ch] = sq; }
  }
  __syncthreads();
  atomicAdd(&gacc[t], red[t]);
}

// ---------------------------------------------------------------------------
// finalize: layernorm (per-channel over B*P) + relu, in place on x chunk
// ---------------------------------------------------------------------------
__global__ __launch_bounds__(256) void finalize_ln(float* __restrict__ x,
                                                   const float* __restrict__ gacc,
                                                   const float* __restrict__ gamma,
                                                   const float* __restrict__ beta) {
  const int idx = blockIdx.x * 256 + threadIdx.x;
  const int fi = idx * 4;
  const int c = (fi >> 12) & 127;
  const float inv = 1.f / 32768.f;
  const float mean = gacc[c] * inv;
  const float var = gacc[128 + c] * inv - mean * mean;
  const float scale = rsqrtf(var + 1e-5f) * gamma[c];
  const float shift = beta[c] - mean * scale;
  float4v v = *(float4v*)(x + fi);
#pragma unroll
  for (int r = 0; r < 4; ++r) v[r] = fmaxf(v[r] * scale + shift, 0.f);
  *(float4v*)(x + fi) = v;
}

extern "C" void kernel_launch(void* const* d_in, const int* in_sizes, int n_in,
                              void* d_out, int out_size, void* d_ws, size_t ws_size,
                              hipStream_t stream) {
  const float* xyz    = (const float*)d_in[0];
  const float* points = (const float*)d_in[1];
  const float* lc     = (const float*)d_in[2];
  const int*   nl     = (const int*)d_in[3];
  const int*   didx   = (const int*)d_in[4];
  const float* Ww     = (const float*)d_in[5];
  const float* bw     = (const float*)d_in[6];
  const float* Wl     = (const float*)d_in[7];
  const float* bl     = (const float*)d_in[8];
  const float* gamma  = (const float*)d_in[9];
  const float* beta   = (const float*)d_in[10];

  float* out  = (float*)d_out;
  float* xout = out + (size_t)Bn * Pn * 3;                       // x chunk (B,C,P)
  unsigned short* WlT = (unsigned short*)d_ws;                   // 512 KB
  float* gacc = (float*)((char*)d_ws + (size_t)512 * 1024);      // 1 KB
  unsigned short* Mglob =
      (unsigned short*)((char*)d_ws + (size_t)1024 * 1024);      // 128 MB

  prep<<<48, 256, 0, stream>>>(Wl, WlT, xyz, out, gacc);
  stage1<<<8192, 64, 0, stream>>>(points, lc, nl, didx, Ww, bw, Mglob);
  stage2<<<1024, 256, 0, stream>>>(Mglob, WlT, bl, xout, gacc);
  finalize_ln<<<4096, 256, 0, stream>>>(xout, gacc, gamma, beta);
}